// Round 4
// baseline (699.048 us; speedup 1.0000x reference)
//
#include <hip/hip_runtime.h>
#include <cstdint>
#include <cmath>

typedef _Float16 f16;
typedef _Float16 f16x8 __attribute__((ext_vector_type(8)));
typedef float f32x4 __attribute__((ext_vector_type(4)));

// ---------------------------------------------------------------------------
// Build X1 = [enc_flat(10240) | word(512) | persona[speaker](512) | h0(512)] fp16
__global__ __launch_bounds__(256) void build_x1_kernel(
    const float* __restrict__ enc, const float* __restrict__ word,
    const float* __restrict__ pers, const int* __restrict__ speaker,
    const float* __restrict__ h0, f16* __restrict__ X)
{
  const int b  = blockIdx.y;
  const int k2 = blockIdx.x * 256 + threadIdx.x;   // 0..5887
  const int k  = k2 * 2;
  float v0, v1;
  if (k < 10240) {
    const float* p = enc + (long long)b * 10240 + k; v0 = p[0]; v1 = p[1];
  } else if (k < 10752) {
    const float* p = word + b * 512 + (k - 10240);   v0 = p[0]; v1 = p[1];
  } else if (k < 11264) {
    const float* p = pers + (long long)speaker[b] * 512 + (k - 10752); v0 = p[0]; v1 = p[1];
  } else {
    const float* p = h0 + b * 512 + (k - 11264);     v0 = p[0]; v1 = p[1];
  }
  union { f16 h[2]; unsigned int u; } pk;
  pk.h[0] = (f16)v0; pk.h[1] = (f16)v1;
  ((unsigned int*)X)[(long long)b * 5888 + k2] = pk.u;
}

// ---------------------------------------------------------------------------
// WsT[L][n][k] = fp16( W_L[k][n] + U_L[k][n] ), n in [0,2048), k in [0,512).
// Valid because layers 2-4 have x == h: z = h @ (W+U).
__global__ __launch_bounds__(256) void wsum_t_kernel(
    const float* __restrict__ W2, const float* __restrict__ U2,
    const float* __restrict__ W3, const float* __restrict__ U3,
    const float* __restrict__ W4, const float* __restrict__ U4,
    f16* __restrict__ out)
{
  const int t = blockIdx.x * 256 + threadIdx.x;   // 16384 threads per layer
  const int L = blockIdx.y;
  const float* W = (L == 0) ? W2 : (L == 1) ? W3 : W4;
  const float* U = (L == 0) ? U2 : (L == 1) ? U3 : U4;
  const int n  = t & 2047;
  const int k0 = (t >> 11) << 6;                  // 8 k-groups of 64
  f16* op = out + (long long)L * (2048 * 512) + (long long)n * 512 + k0;
  for (int kk = 0; kk < 64; kk += 8) {
    f16x8 v;
    #pragma unroll
    for (int j = 0; j < 8; j++) {
      const int k = k0 + kk + j;
      v[j] = (f16)(W[(long long)k * 2048 + n] + U[(long long)k * 2048 + n]);
    }
    *(f16x8*)(op + kk) = v;
  }
}

// ---------------------------------------------------------------------------
// Barrier-free direct-register MFMA GEMM. Wave tile = 128m x 32n.
// No LDS, no __syncthreads: A loaded f16x8 in MFMA A-layout from global,
// B loaded as 8 strided fp32 scalars/lane -> cvt f16. Register double-buffer.
// wid decompose: mt = wid&1 (paired so both m-tiles of the same B columns
// share a CU -> B HBM-fetched once), nt = (wid>>1)%ntiles, ks = rest (split-K).
__global__ __launch_bounds__(256, 2) void gemm_direct(
    const f16* __restrict__ A, int lda,
    const float* __restrict__ B0, const float* __restrict__ B1, int ksw, int ldb,
    int ntiles, int kchunk,
    void* __restrict__ Cv, int ldc, long long c_split_stride, int store_f16)
{
  const int lane = threadIdx.x & 63;
  const int wid  = blockIdx.x * 4 + (threadIdx.x >> 6);
  const int mt = wid & 1;
  const int nt = (wid >> 1) % ntiles;
  const int ks = wid / (2 * ntiles);
  const int m0 = mt * 128;
  const int n0 = nt * 32;
  const int kbeg = ks * kchunk;
  const int lj = lane & 15, quad = lane >> 4;

  f32x4 acc[8][2] = {};

  const f16* Abase = A + (long long)(m0 + lj) * lda + quad * 8;
  const int bn0 = n0 + lj, bn1 = n0 + 16 + lj;

  f16x8 a_buf[2][8];
  float b_buf[2][2][8];

  auto loadA = [&](int k, f16x8* dst) {
    #pragma unroll
    for (int mf = 0; mf < 8; mf++)
      dst[mf] = *(const f16x8*)(Abase + (long long)mf * 16 * lda + k);
  };
  auto loadB = [&](int k, float (*bd)[8]) {
    const int krow = k + quad * 8;     // 8-row span never crosses ksw (8 | ksw)
    const float* bp = (krow >= ksw) ? (B1 + (long long)(krow - ksw) * ldb)
                                    : (B0 + (long long)krow * ldb);
    #pragma unroll
    for (int j = 0; j < 8; j++) {
      bd[0][j] = bp[(long long)j * ldb + bn0];
      bd[1][j] = bp[(long long)j * ldb + bn1];
    }
  };

  loadB(kbeg, b_buf[0]);
  loadA(kbeg, a_buf[0]);
  const int niter = kchunk >> 5;
  #pragma unroll 2
  for (int kt = 0; kt < niter; kt++) {
    const int cb = kt & 1;
    if (kt + 1 < niter) {
      loadB(kbeg + (kt + 1) * 32, b_buf[cb ^ 1]);
      loadA(kbeg + (kt + 1) * 32, a_buf[cb ^ 1]);
    }
    f16x8 bf[2];
    #pragma unroll
    for (int nf = 0; nf < 2; nf++)
      #pragma unroll
      for (int j = 0; j < 8; j++) bf[nf][j] = (f16)b_buf[cb][nf][j];
    #pragma unroll
    for (int mf = 0; mf < 8; mf++)
      #pragma unroll
      for (int nf = 0; nf < 2; nf++)
        acc[mf][nf] = __builtin_amdgcn_mfma_f32_16x16x32_f16(a_buf[cb][mf], bf[nf], acc[mf][nf], 0, 0, 0);
  }

  // C/D: col = lane&15, row = quad*4 + r
  if (store_f16) {
    f16* Cs = (f16*)Cv + (long long)ks * c_split_stride;
    #pragma unroll
    for (int mf = 0; mf < 8; mf++) {
      const int r0 = m0 + mf * 16 + quad * 4;
      #pragma unroll
      for (int nf = 0; nf < 2; nf++) {
        const int cc = n0 + nf * 16 + lj;
        #pragma unroll
        for (int r = 0; r < 4; r++)
          Cs[(long long)(r0 + r) * ldc + cc] = (f16)acc[mf][nf][r];
      }
    }
  } else {
    float* Cs = (float*)Cv + (long long)ks * c_split_stride;
    #pragma unroll
    for (int mf = 0; mf < 8; mf++) {
      const int r0 = m0 + mf * 16 + quad * 4;
      #pragma unroll
      for (int nf = 0; nf < 2; nf++) {
        const int cc = n0 + nf * 16 + lj;
        #pragma unroll
        for (int r = 0; r < 4; r++)
          Cs[(long long)(r0 + r) * ldc + cc] = acc[mf][nf][r];
      }
    }
  }
}

// ---------------------------------------------------------------------------
// Small LSTM layer, barrier-free, all in-register. One wave per block.
// Wave tile: 32 m x 16 j x 4 gates, K = 512 (z = h @ (W+U), fp16 WsT).
// Gates for a cell land in different acc regs of the SAME lane -> in-register
// epilogue, no partials, no LDS.
__global__ __launch_bounds__(64) void lstm_small_layer(
    const f16* __restrict__ h_in,          // [256][512] fp16
    const f16* __restrict__ WsT,           // [2048][512] fp16 (W+U)^T
    const float* __restrict__ bias,
    const float* __restrict__ c_prev, float* __restrict__ c_out,
    f16* __restrict__ h16_out, float* __restrict__ h32_out)
{
  const int lane = threadIdx.x;
  const int wid  = blockIdx.x;           // 256 waves
  const int jt = wid & 31, mt = wid >> 5;
  const int m0 = mt * 32, j0 = jt * 16;
  const int lj = lane & 15, quad = lane >> 4;

  f32x4 acc[2][4] = {};
  const f16* Ab = h_in + (long long)(m0 + lj) * 512 + quad * 8;
  const f16* Bb = WsT + (long long)(j0 + lj) * 512 + quad * 8;

  f16x8 a_buf[2][2], b_buf[2][4];
  auto load = [&](int k, f16x8* a, f16x8* b) {
    a[0] = *(const f16x8*)(Ab + k);
    a[1] = *(const f16x8*)(Ab + 16 * 512 + k);
    #pragma unroll
    for (int g = 0; g < 4; g++)
      b[g] = *(const f16x8*)(Bb + (long long)g * 512 * 512 + k);
  };
  load(0, a_buf[0], b_buf[0]);
  #pragma unroll 2
  for (int kt = 0; kt < 16; kt++) {
    const int cb = kt & 1;
    if (kt < 15) load((kt + 1) * 32, a_buf[cb ^ 1], b_buf[cb ^ 1]);
    #pragma unroll
    for (int mf = 0; mf < 2; mf++)
      #pragma unroll
      for (int g = 0; g < 4; g++)
        acc[mf][g] = __builtin_amdgcn_mfma_f32_16x16x32_f16(a_buf[cb][mf], b_buf[cb][g], acc[mf][g], 0, 0, 0);
  }

  const float bi = bias[j0 + lj],        bfv = bias[512 + j0 + lj];
  const float bg = bias[1024 + j0 + lj], bo  = bias[1536 + j0 + lj];
  #pragma unroll
  for (int mf = 0; mf < 2; mf++) {
    #pragma unroll
    for (int r = 0; r < 4; r++) {
      const int m = m0 + mf * 16 + quad * 4 + r;
      const int idx = m * 512 + j0 + lj;
      const float gi = 1.f / (1.f + expf(-(acc[mf][0][r] + bi)));
      const float gf = 1.f / (1.f + expf(-(acc[mf][1][r] + bfv)));
      const float gg = fmaxf(acc[mf][2][r] + bg, 0.f);
      const float go = 1.f / (1.f + expf(-(acc[mf][3][r] + bo)));
      const float cn = gf * c_prev[idx] + gi * gg;
      const float hn = go * fmaxf(cn, 0.f);
      c_out[idx] = cn;
      h16_out[idx] = (f16)hn;
      if (h32_out) h32_out[idx] = hn;
    }
  }
}

// ---------------------------------------------------------------------------
// L1 gate: reduce 8 fp16 split-K partials + bias, apply gates. 2 cols/thread.
__global__ __launch_bounds__(256) void gate_kernel(
    const unsigned int* __restrict__ zbase, const float* __restrict__ bias,
    const float* __restrict__ c_prev, float* __restrict__ c_out,
    f16* __restrict__ h16_out)
{
  const int idx2 = blockIdx.x * 256 + threadIdx.x;  // 0..65535
  const int b  = idx2 >> 8;
  const int j2 = idx2 & 255;
  const int j  = j2 * 2;
  float z[4][2];
  #pragma unroll
  for (int g = 0; g < 4; g++) { z[g][0] = bias[g * 512 + j]; z[g][1] = bias[g * 512 + j + 1]; }
  for (int s = 0; s < 8; s++) {
    const unsigned int* zp = zbase + s * 262144 + b * 1024;
    #pragma unroll
    for (int g = 0; g < 4; g++) {
      union { unsigned int u; f16 h[2]; } v;
      v.u = zp[g * 256 + j2];
      z[g][0] += (float)v.h[0];
      z[g][1] += (float)v.h[1];
    }
  }
  #pragma unroll
  for (int e = 0; e < 2; e++) {
    const float gi = 1.f / (1.f + expf(-z[0][e]));
    const float gf = 1.f / (1.f + expf(-z[1][e]));
    const float gg = fmaxf(z[2][e], 0.f);
    const float go = 1.f / (1.f + expf(-z[3][e]));
    const int idx = b * 512 + j + e;
    const float cn = gf * c_prev[idx] + gi * gg;
    const float hn = go * fmaxf(cn, 0.f);
    c_out[idx] = cn;
    h16_out[idx] = (f16)hn;
  }
}

// ---------------------------------------------------------------------------
// In-place softmax over V=32000 per row, float4 path. 1024 thr/row.
__global__ __launch_bounds__(1024) void softmax_kernel(
    float* __restrict__ logits, const float* __restrict__ bd)
{
  const int row = blockIdx.x;
  const int t = threadIdx.x;
  float4* rp = (float4*)(logits + (long long)row * 32000);   // 8000 float4
  const float4* bp = (const float4*)bd;
  float4 l[8];
  float m = -1e30f;
  #pragma unroll
  for (int i = 0; i < 8; i++) {
    const int v = t + i * 1024;
    if (v < 8000) {
      float4 x = rp[v]; const float4 bb = bp[v];
      x.x += bb.x; x.y += bb.y; x.z += bb.z; x.w += bb.w;
      l[i] = x;
      m = fmaxf(m, fmaxf(fmaxf(x.x, x.y), fmaxf(x.z, x.w)));
    } else {
      l[i] = make_float4(-1e30f, -1e30f, -1e30f, -1e30f);
    }
  }
  #pragma unroll
  for (int off = 32; off > 0; off >>= 1) m = fmaxf(m, __shfl_xor(m, off, 64));
  __shared__ float redm[16];
  __shared__ float reds[16];
  const int w = t >> 6;
  if ((t & 63) == 0) redm[w] = m;
  __syncthreads();
  float bm = redm[0];
  #pragma unroll
  for (int i = 1; i < 16; i++) bm = fmaxf(bm, redm[i]);
  float s = 0.f;
  #pragma unroll
  for (int i = 0; i < 8; i++) {
    const float ex = expf(l[i].x - bm), ey = expf(l[i].y - bm);
    const float ez = expf(l[i].z - bm), ew = expf(l[i].w - bm);
    l[i] = make_float4(ex, ey, ez, ew);
    s += (ex + ey) + (ez + ew);
  }
  #pragma unroll
  for (int off = 32; off > 0; off >>= 1) s += __shfl_xor(s, off, 64);
  if ((t & 63) == 0) reds[w] = s;
  __syncthreads();
  float ts = 0.f;
  #pragma unroll
  for (int i = 0; i < 16; i++) ts += reds[i];
  const float inv = 1.0f / ts;
  #pragma unroll
  for (int i = 0; i < 8; i++) {
    const int v = t + i * 1024;
    if (v < 8000) {
      float4 x = l[i];
      x.x *= inv; x.y *= inv; x.z *= inv; x.w *= inv;
      rp[v] = x;
    }
  }
}

// ---------------------------------------------------------------------------
extern "C" void kernel_launch(void* const* d_in, const int* in_sizes, int n_in,
                              void* d_out, int out_size, void* d_ws, size_t ws_size,
                              hipStream_t stream) {
  const float* enc     = (const float*)d_in[0];
  const float* word    = (const float*)d_in[1];
  const float* h0      = (const float*)d_in[2];
  const float* c0      = (const float*)d_in[3];
  const int*   speaker = (const int*)d_in[4];
  const float* pers = (const float*)d_in[6];
  const float* W1 = (const float*)d_in[7];
  const float* U1 = (const float*)d_in[8];
  const float* b1 = (const float*)d_in[9];
  const float* W2 = (const float*)d_in[10];
  const float* U2 = (const float*)d_in[11];
  const float* b2 = (const float*)d_in[12];
  const float* W3 = (const float*)d_in[13];
  const float* U3 = (const float*)d_in[14];
  const float* b3 = (const float*)d_in[15];
  const float* W4 = (const float*)d_in[16];
  const float* U4 = (const float*)d_in[17];
  const float* b4 = (const float*)d_in[18];
  const float* Wd = (const float*)d_in[19];
  const float* bd = (const float*)d_in[20];

  float* out = (float*)d_out;
  // d_out scratch layout (all consumed before decoder overwrites [0,31.25MB)):
  //   [0, 8 MB)        : 8 fp16 split-K z partials (1 MB each)
  //   [8, 14 MB)       : WsT fp16, 3 x [2048][512]  (W+U)^T for layers 2-4
  //   [16, 22.8 MB)    : X1 fp16 (256 x 11776)
  //   [24, 24.5 MB)    : c chain buffer (fp32, 256x512)
  f16*   zp16  = (f16*)d_out;
  f16*   WsT   = (f16*)((char*)d_out + 8388608);
  f16*   X1h   = (f16*)((char*)d_out + 16777216);
  float* cbuf  = out + 6291456;            // 24 MB
  float* h4_out = out + 8192000;
  float* c4_out = out + 8192000 + 131072;

  f16* hA = (f16*)d_ws;                          // 256 KB
  f16* hB = (f16*)((char*)d_ws + 262144);        // 256 KB
  f16* hC = (f16*)((char*)d_ws + 524288);        // 256 KB

  const int BIG = 1 << 29;
  const long long LW = 2048LL * 512;

  build_x1_kernel<<<dim3(23, 256), 256, 0, stream>>>(enc, word, pers, speaker, h0, X1h);
  wsum_t_kernel<<<dim3(64, 3), 256, 0, stream>>>(W2, U2, W3, U3, W4, U4, WsT);

  // layer 1: K = 11776, split-K 8 x 1472; waves = 2 x 64 x 8 = 1024 -> 256 blocks
  gemm_direct<<<dim3(256), 256, 0, stream>>>(
      X1h, 11776, W1, U1, 11264, 2048, 64, 1472, zp16, 2048, 524288LL, 1);
  gate_kernel<<<dim3(256), 256, 0, stream>>>((const unsigned int*)zp16, b1, c0, cbuf, hA);

  // layers 2-4: z = h @ (W+U), K=512, 256 single-wave blocks each
  lstm_small_layer<<<dim3(256), 64, 0, stream>>>(hA, WsT,          b2, cbuf, cbuf, hB, nullptr);
  lstm_small_layer<<<dim3(256), 64, 0, stream>>>(hB, WsT + LW,     b3, cbuf, cbuf, hA, nullptr);
  lstm_small_layer<<<dim3(256), 64, 0, stream>>>(hA, WsT + 2 * LW, b4, cbuf, c4_out, hC, h4_out);

  // decoder: logits = h4 @ Wd; waves = 2 x 1000 -> 500 blocks
  gemm_direct<<<dim3(500), 256, 0, stream>>>(
      hC, 512, Wd, Wd, BIG, 32000, 1000, 512, out, 32000, 0LL, 0);

  softmax_kernel<<<dim3(256), 1024, 0, stream>>>(out, bd);
}

// Round 5
// 340.033 us; speedup vs baseline: 2.0558x; 2.0558x over previous
//
#include <hip/hip_runtime.h>
#include <cstdint>
#include <cmath>

typedef _Float16 f16;
typedef _Float16 f16x8 __attribute__((ext_vector_type(8)));
typedef float f32x4 __attribute__((ext_vector_type(4)));

// async 16B/lane global->LDS (lds dst = wave-uniform base + lane*16)
__device__ inline void gld_lds16(const void* g, void* l) {
  __builtin_amdgcn_global_load_lds(
      (__attribute__((address_space(1))) void*)(uintptr_t)g,
      (__attribute__((address_space(3))) void*)l, 16, 0, 0);
}

// ---------------------------------------------------------------------------
// Build X1 = [enc_flat(10240) | word(512) | persona[speaker](512) | h0(512)] fp16
__global__ __launch_bounds__(256) void build_x1_kernel(
    const float* __restrict__ enc, const float* __restrict__ word,
    const float* __restrict__ pers, const int* __restrict__ speaker,
    const float* __restrict__ h0, f16* __restrict__ X)
{
  const int b  = blockIdx.y;
  const int k2 = blockIdx.x * 256 + threadIdx.x;   // 0..5887
  const int k  = k2 * 2;
  float v0, v1;
  if (k < 10240) {
    const float* p = enc + (long long)b * 10240 + k; v0 = p[0]; v1 = p[1];
  } else if (k < 10752) {
    const float* p = word + b * 512 + (k - 10240);   v0 = p[0]; v1 = p[1];
  } else if (k < 11264) {
    const float* p = pers + (long long)speaker[b] * 512 + (k - 10752); v0 = p[0]; v1 = p[1];
  } else {
    const float* p = h0 + b * 512 + (k - 11264);     v0 = p[0]; v1 = p[1];
  }
  union { f16 h[2]; unsigned int u; } pk;
  pk.h[0] = (f16)v0; pk.h[1] = (f16)v1;
  ((unsigned int*)X)[(long long)b * 5888 + k2] = pk.u;
}

// ---------------------------------------------------------------------------
// WsT[L][n][k] = fp16( W_L[k][n] + U_L[k][n] ) — valid because layers 2-4
// have x == h: z = h @ (W+U).
__global__ __launch_bounds__(256) void wsum_t_kernel(
    const float* __restrict__ W2, const float* __restrict__ U2,
    const float* __restrict__ W3, const float* __restrict__ U3,
    const float* __restrict__ W4, const float* __restrict__ U4,
    f16* __restrict__ out)
{
  const int t = blockIdx.x * 256 + threadIdx.x;   // 16384 threads per layer
  const int L = blockIdx.y;
  const float* W = (L == 0) ? W2 : (L == 1) ? W3 : W4;
  const float* U = (L == 0) ? U2 : (L == 1) ? U3 : U4;
  const int n  = t & 2047;
  const int k0 = (t >> 11) << 6;                  // 8 k-groups of 64
  f16* op = out + (long long)L * (2048 * 512) + (long long)n * 512 + k0;
  for (int kk = 0; kk < 64; kk += 8) {
    f16x8 v;
    #pragma unroll
    for (int j = 0; j < 8; j++) {
      const int k = k0 + kk + j;
      v[j] = (f16)(W[(long long)k * 2048 + n] + U[(long long)k * 2048 + n]);
    }
    *(f16x8*)(op + kk) = v;
  }
}

// ---------------------------------------------------------------------------
// Pipelined fp16 MFMA GEMM (R3-proven): BM=128 BN=128 BK=32, 4 waves 2x2,
// wave tile 64x64, double-buffered LDS, prefetch of iter k+1 before compute
// of iter k. A fp16 via global_load_lds (chunk-swizzled rows of 32h).
// B fp32->fp16, float2/thread, [n][40] padded. blockIdx.z = split-K slice.
__global__ __launch_bounds__(256, 2) void gemm_f16_pipe(
    const f16* __restrict__ A, int lda,
    const float* __restrict__ B0, const float* __restrict__ B1, int ksw, int ldb,
    void* __restrict__ Cv, int ldc, long long c_split_stride, int niter,
    int store_f16)
{
  __shared__ __align__(16) f16 Ah[2][128 * 32];   // 2 x 8 KB
  __shared__ __align__(16) f16 Bh[2][128 * 40];   // 2 x 10 KB

  const int tid  = threadIdx.x;
  const int lane = tid & 63;
  const int wave = tid >> 6;
  const int m0 = blockIdx.x * 128;
  const int n0 = blockIdx.y * 128;
  const int kbeg = blockIdx.z * (niter * 32);

  const int a_row16 = lane >> 2;
  const int a_ksub  = ((lane & 3) ^ ((lane >> 3) & 3)) * 8;

  const int nl0  = (tid & 63) * 2;
  const int koct = tid >> 6;          // 0..3

  float2 bv[8];

  auto issueB = [&](int kt) {
    const int kb = kbeg + kt * 32 + koct * 8;
    #pragma unroll
    for (int i = 0; i < 8; i++) {
      const int krow = kb + i;
      const float* bp = (krow >= ksw) ? (B1 + (long long)(krow - ksw) * ldb)
                                      : (B0 + (long long)krow * ldb);
      bv[i] = *(const float2*)(bp + n0 + nl0);
    }
  };
  auto issueA = [&](int kt) {
    const int akb = kbeg + kt * 32;
    #pragma unroll
    for (int half = 0; half < 2; half++) {
      const int rb = wave * 32 + half * 16;
      const f16* gp = A + (long long)(m0 + rb + a_row16) * lda + akb + a_ksub;
      gld_lds16((const void*)gp, (void*)&Ah[kt & 1][rb * 32]);
    }
  };
  auto writeB = [&](int kt) {
    f16x8 p0, p1;
    #pragma unroll
    for (int i = 0; i < 8; i++) { p0[i] = (f16)bv[i].x; p1[i] = (f16)bv[i].y; }
    *(f16x8*)&Bh[kt & 1][(nl0    ) * 40 + koct * 8] = p0;
    *(f16x8*)&Bh[kt & 1][(nl0 + 1) * 40 + koct * 8] = p1;
  };

  const int wm = (wave & 1) * 64;
  const int wn = (wave >> 1) * 64;
  f32x4 acc[4][4] = {};

  issueB(0); issueA(0); writeB(0);
  __syncthreads();

  for (int kt = 0; kt < niter; kt++) {
    const int buf = kt & 1;
    const bool more = (kt + 1 < niter);
    if (more) { issueB(kt + 1); issueA(kt + 1); }

    f16x8 af[4], bf[4];
    #pragma unroll
    for (int mi = 0; mi < 4; mi++) {
      const int m = wm + mi * 16 + (lane & 15);
      af[mi] = *(const f16x8*)&Ah[buf][m * 32 + (((lane >> 4) ^ ((m >> 1) & 3)) * 8)];
    }
    #pragma unroll
    for (int ni = 0; ni < 4; ni++) {
      const int n = wn + ni * 16 + (lane & 15);
      bf[ni] = *(const f16x8*)&Bh[buf][n * 40 + (lane >> 4) * 8];
    }
    #pragma unroll
    for (int mi = 0; mi < 4; mi++)
      #pragma unroll
      for (int ni = 0; ni < 4; ni++)
        acc[mi][ni] = __builtin_amdgcn_mfma_f32_16x16x32_f16(af[mi], bf[ni], acc[mi][ni], 0, 0, 0);

    if (more) writeB(kt + 1);
    __syncthreads();
  }

  // C/D: col = lane&15, row = (lane>>4)*4 + r
  if (store_f16) {
    f16* Cs = (f16*)Cv + (long long)blockIdx.z * c_split_stride;
    #pragma unroll
    for (int mi = 0; mi < 4; mi++) {
      const int r0 = m0 + wm + mi * 16 + (lane >> 4) * 4;
      #pragma unroll
      for (int ni = 0; ni < 4; ni++) {
        const int cc = n0 + wn + ni * 16 + (lane & 15);
        #pragma unroll
        for (int r = 0; r < 4; r++)
          Cs[(long long)(r0 + r) * ldc + cc] = (f16)acc[mi][ni][r];
      }
    }
  } else {
    float* Cs = (float*)Cv + (long long)blockIdx.z * c_split_stride;
    #pragma unroll
    for (int mi = 0; mi < 4; mi++) {
      const int r0 = m0 + wm + mi * 16 + (lane >> 4) * 4;
      #pragma unroll
      for (int ni = 0; ni < 4; ni++) {
        const int cc = n0 + wn + ni * 16 + (lane & 15);
        #pragma unroll
        for (int r = 0; r < 4; r++)
          Cs[(long long)(r0 + r) * ldc + cc] = acc[mi][ni][r];
      }
    }
  }
}

// ---------------------------------------------------------------------------
// Small LSTM layer, barrier-free, in-register, NO arrays / NO pointer-lambdas
// (R4's spill bug). One wave per block, wave tile 32m x 16j x 4 gates, K=512.
// Fully unrolled explicit double buffer -> pure SSA -> no scratch.
__global__ __launch_bounds__(64) void lstm_small_layer(
    const f16* __restrict__ h_in,          // [256][512] fp16
    const f16* __restrict__ WsT,           // [2048][512] fp16 (W+U)^T
    const float* __restrict__ bias,
    const float* __restrict__ c_prev, float* __restrict__ c_out,
    f16* __restrict__ h16_out, float* __restrict__ h32_out)
{
  const int lane = threadIdx.x;
  const int wid  = blockIdx.x;           // 256 waves
  const int jt = wid & 31, mt = wid >> 5;
  const int m0 = mt * 32, j0 = jt * 16;
  const int lj = lane & 15, quad = lane >> 4;

  const f16* Ab = h_in + (long long)(m0 + lj) * 512 + quad * 8;
  const f16* Bb = WsT + (long long)(j0 + lj) * 512 + quad * 8;
  const long long GS = 512LL * 512;      // gate stride in WsT

  f32x4 a00 = {}, a01 = {}, a02 = {}, a03 = {};
  f32x4 a10 = {}, a11 = {}, a12 = {}, a13 = {};

  f16x8 ca0 = *(const f16x8*)(Ab);
  f16x8 ca1 = *(const f16x8*)(Ab + 16 * 512);
  f16x8 cb0 = *(const f16x8*)(Bb);
  f16x8 cb1 = *(const f16x8*)(Bb + GS);
  f16x8 cb2 = *(const f16x8*)(Bb + 2 * GS);
  f16x8 cb3 = *(const f16x8*)(Bb + 3 * GS);

  #pragma unroll
  for (int kt = 0; kt < 16; kt++) {
    f16x8 na0 = ca0, na1 = ca1, nb0 = cb0, nb1 = cb1, nb2 = cb2, nb3 = cb3;
    if (kt < 15) {
      const int k = (kt + 1) * 32;
      na0 = *(const f16x8*)(Ab + k);
      na1 = *(const f16x8*)(Ab + 16 * 512 + k);
      nb0 = *(const f16x8*)(Bb + k);
      nb1 = *(const f16x8*)(Bb + GS + k);
      nb2 = *(const f16x8*)(Bb + 2 * GS + k);
      nb3 = *(const f16x8*)(Bb + 3 * GS + k);
    }
    a00 = __builtin_amdgcn_mfma_f32_16x16x32_f16(ca0, cb0, a00, 0, 0, 0);
    a01 = __builtin_amdgcn_mfma_f32_16x16x32_f16(ca0, cb1, a01, 0, 0, 0);
    a02 = __builtin_amdgcn_mfma_f32_16x16x32_f16(ca0, cb2, a02, 0, 0, 0);
    a03 = __builtin_amdgcn_mfma_f32_16x16x32_f16(ca0, cb3, a03, 0, 0, 0);
    a10 = __builtin_amdgcn_mfma_f32_16x16x32_f16(ca1, cb0, a10, 0, 0, 0);
    a11 = __builtin_amdgcn_mfma_f32_16x16x32_f16(ca1, cb1, a11, 0, 0, 0);
    a12 = __builtin_amdgcn_mfma_f32_16x16x32_f16(ca1, cb2, a12, 0, 0, 0);
    a13 = __builtin_amdgcn_mfma_f32_16x16x32_f16(ca1, cb3, a13, 0, 0, 0);
    ca0 = na0; ca1 = na1; cb0 = nb0; cb1 = nb1; cb2 = nb2; cb3 = nb3;
  }

  const float bi = bias[j0 + lj],        bfv = bias[512 + j0 + lj];
  const float bg = bias[1024 + j0 + lj], bo  = bias[1536 + j0 + lj];
  #pragma unroll
  for (int r = 0; r < 4; r++) {
    // mf = 0
    {
      const int m = m0 + quad * 4 + r;
      const int idx = m * 512 + j0 + lj;
      const float gi = 1.f / (1.f + expf(-(a00[r] + bi)));
      const float gf = 1.f / (1.f + expf(-(a01[r] + bfv)));
      const float gg = fmaxf(a02[r] + bg, 0.f);
      const float go = 1.f / (1.f + expf(-(a03[r] + bo)));
      const float cn = gf * c_prev[idx] + gi * gg;
      const float hn = go * fmaxf(cn, 0.f);
      c_out[idx] = cn;
      h16_out[idx] = (f16)hn;
      if (h32_out) h32_out[idx] = hn;
    }
    // mf = 1
    {
      const int m = m0 + 16 + quad * 4 + r;
      const int idx = m * 512 + j0 + lj;
      const float gi = 1.f / (1.f + expf(-(a10[r] + bi)));
      const float gf = 1.f / (1.f + expf(-(a11[r] + bfv)));
      const float gg = fmaxf(a12[r] + bg, 0.f);
      const float go = 1.f / (1.f + expf(-(a13[r] + bo)));
      const float cn = gf * c_prev[idx] + gi * gg;
      const float hn = go * fmaxf(cn, 0.f);
      c_out[idx] = cn;
      h16_out[idx] = (f16)hn;
      if (h32_out) h32_out[idx] = hn;
    }
  }
}

// ---------------------------------------------------------------------------
// L1 gate: reduce 16 fp16 split-K partials + bias, apply gates. 2 cols/thread.
__global__ __launch_bounds__(256) void gate_kernel(
    const unsigned int* __restrict__ zbase, const float* __restrict__ bias,
    const float* __restrict__ c_prev, float* __restrict__ c_out,
    f16* __restrict__ h16_out)
{
  const int idx2 = blockIdx.x * 256 + threadIdx.x;  // 0..65535
  const int b  = idx2 >> 8;
  const int j2 = idx2 & 255;
  const int j  = j2 * 2;
  float z[4][2];
  #pragma unroll
  for (int g = 0; g < 4; g++) { z[g][0] = bias[g * 512 + j]; z[g][1] = bias[g * 512 + j + 1]; }
  for (int s = 0; s < 16; s++) {
    const unsigned int* zp = zbase + s * 262144 + b * 1024;
    #pragma unroll
    for (int g = 0; g < 4; g++) {
      union { unsigned int u; f16 h[2]; } v;
      v.u = zp[g * 256 + j2];
      z[g][0] += (float)v.h[0];
      z[g][1] += (float)v.h[1];
    }
  }
  #pragma unroll
  for (int e = 0; e < 2; e++) {
    const float gi = 1.f / (1.f + expf(-z[0][e]));
    const float gf = 1.f / (1.f + expf(-z[1][e]));
    const float gg = fmaxf(z[2][e], 0.f);
    const float go = 1.f / (1.f + expf(-z[3][e]));
    const int idx = b * 512 + j + e;
    const float cn = gf * c_prev[idx] + gi * gg;
    const float hn = go * fmaxf(cn, 0.f);
    c_out[idx] = cn;
    h16_out[idx] = (f16)hn;
  }
}

// ---------------------------------------------------------------------------
// In-place softmax over V=32000 per row, float4 path. 1024 thr/row.
__global__ __launch_bounds__(1024) void softmax_kernel(
    float* __restrict__ logits, const float* __restrict__ bd)
{
  const int row = blockIdx.x;
  const int t = threadIdx.x;
  float4* rp = (float4*)(logits + (long long)row * 32000);   // 8000 float4
  const float4* bp = (const float4*)bd;
  float4 l[8];
  float m = -1e30f;
  #pragma unroll
  for (int i = 0; i < 8; i++) {
    const int v = t + i * 1024;
    if (v < 8000) {
      float4 x = rp[v]; const float4 bb = bp[v];
      x.x += bb.x; x.y += bb.y; x.z += bb.z; x.w += bb.w;
      l[i] = x;
      m = fmaxf(m, fmaxf(fmaxf(x.x, x.y), fmaxf(x.z, x.w)));
    } else {
      l[i] = make_float4(-1e30f, -1e30f, -1e30f, -1e30f);
    }
  }
  #pragma unroll
  for (int off = 32; off > 0; off >>= 1) m = fmaxf(m, __shfl_xor(m, off, 64));
  __shared__ float redm[16];
  __shared__ float reds[16];
  const int w = t >> 6;
  if ((t & 63) == 0) redm[w] = m;
  __syncthreads();
  float bm = redm[0];
  #pragma unroll
  for (int i = 1; i < 16; i++) bm = fmaxf(bm, redm[i]);
  float s = 0.f;
  #pragma unroll
  for (int i = 0; i < 8; i++) {
    const float ex = expf(l[i].x - bm), ey = expf(l[i].y - bm);
    const float ez = expf(l[i].z - bm), ew = expf(l[i].w - bm);
    l[i] = make_float4(ex, ey, ez, ew);
    s += (ex + ey) + (ez + ew);
  }
  #pragma unroll
  for (int off = 32; off > 0; off >>= 1) s += __shfl_xor(s, off, 64);
  if ((t & 63) == 0) reds[w] = s;
  __syncthreads();
  float ts = 0.f;
  #pragma unroll
  for (int i = 0; i < 16; i++) ts += reds[i];
  const float inv = 1.0f / ts;
  #pragma unroll
  for (int i = 0; i < 8; i++) {
    const int v = t + i * 1024;
    if (v < 8000) {
      float4 x = l[i];
      x.x *= inv; x.y *= inv; x.z *= inv; x.w *= inv;
      rp[v] = x;
    }
  }
}

// ---------------------------------------------------------------------------
extern "C" void kernel_launch(void* const* d_in, const int* in_sizes, int n_in,
                              void* d_out, int out_size, void* d_ws, size_t ws_size,
                              hipStream_t stream) {
  const float* enc     = (const float*)d_in[0];
  const float* word    = (const float*)d_in[1];
  const float* h0      = (const float*)d_in[2];
  const float* c0      = (const float*)d_in[3];
  const int*   speaker = (const int*)d_in[4];
  const float* pers = (const float*)d_in[6];
  const float* W1 = (const float*)d_in[7];
  const float* U1 = (const float*)d_in[8];
  const float* b1 = (const float*)d_in[9];
  const float* W2 = (const float*)d_in[10];
  const float* U2 = (const float*)d_in[11];
  const float* b2 = (const float*)d_in[12];
  const float* W3 = (const float*)d_in[13];
  const float* U3 = (const float*)d_in[14];
  const float* b3 = (const float*)d_in[15];
  const float* W4 = (const float*)d_in[16];
  const float* U4 = (const float*)d_in[17];
  const float* b4 = (const float*)d_in[18];
  const float* Wd = (const float*)d_in[19];
  const float* bd = (const float*)d_in[20];

  float* out = (float*)d_out;
  // d_out scratch (consumed before decoder writes logits over [0, 31.25MB)):
  //   [0, 16 MB)       : 16 fp16 split-K z partials (1 MB each)
  //   [16, 22.8 MB)    : X1 fp16 (256 x 11776)
  f16*   zp16  = (f16*)d_out;
  f16*   X1h   = (f16*)((char*)d_out + 16777216);
  float* h4_out = out + 8192000;
  float* c4_out = out + 8192000 + 131072;

  // d_ws (>= 8 MB needed; harness provides much more):
  f16*   hA   = (f16*)d_ws;                            // 256 KB
  f16*   hB   = (f16*)((char*)d_ws + 262144);          // 256 KB
  f16*   hC   = (f16*)((char*)d_ws + 524288);          // 256 KB
  float* cbuf = (float*)((char*)d_ws + 786432);        // 512 KB
  f16*   WsT  = (f16*)((char*)d_ws + 2097152);         // 6 MB

  const int BIG = 1 << 29;
  const long long LW = 2048LL * 512;

  build_x1_kernel<<<dim3(23, 256), 256, 0, stream>>>(enc, word, pers, speaker, h0, X1h);
  wsum_t_kernel<<<dim3(64, 3), 256, 0, stream>>>(W2, U2, W3, U3, W4, U4, WsT);

  // layer 1: K = 11776 = 16 splits x 736; grid 2x16x16 = 512 blocks
  gemm_f16_pipe<<<dim3(2, 16, 16), 256, 0, stream>>>(
      X1h, 11776, W1, U1, 11264, 2048, zp16, 2048, 524288LL, 23, 1);
  gate_kernel<<<dim3(256), 256, 0, stream>>>((const unsigned int*)zp16, b1, c0, cbuf, hA);

  // layers 2-4: z = h @ (W+U), K=512, 256 single-wave blocks each
  lstm_small_layer<<<dim3(256), 64, 0, stream>>>(hA, WsT,          b2, cbuf, cbuf, hB, nullptr);
  lstm_small_layer<<<dim3(256), 64, 0, stream>>>(hB, WsT + LW,     b3, cbuf, cbuf, hA, nullptr);
  lstm_small_layer<<<dim3(256), 64, 0, stream>>>(hA, WsT + 2 * LW, b4, cbuf, c4_out, hC, h4_out);

  // decoder: logits = h4 @ Wd, fp32 in place; grid 2x250 = 500 blocks
  gemm_f16_pipe<<<dim3(2, 250, 1), 256, 0, stream>>>(
      hC, 512, Wd, Wd, BIG, 32000, out, 32000, 0LL, 16, 0);

  softmax_kernel<<<dim3(256), 1024, 0, stream>>>(out, bd);
}